// Round 1
// baseline (334.281 us; speedup 1.0000x reference)
//
#include <hip/hip_runtime.h>
#include <hip/hip_bf16.h>

#define B_ 64
#define H_ 1024
#define S_ 1024
#define V_ 50257
#define L_ 3
#define G3H 3072   // 3*H
#define N_GATES 6144  // 2*3H fused gi|gh

// ---------------------------------------------------------------------------
// Embedding gather: x0[b][h] = emb[seq[b]][h]
__global__ __launch_bounds__(256) void embed_k(const int* __restrict__ seq,
                                               const float* __restrict__ emb,
                                               float* __restrict__ x0) {
    int idx = blockIdx.x * 256 + threadIdx.x;          // 65536 total
    int b = idx >> 10, h = idx & 1023;
    x0[idx] = emb[(size_t)seq[b] * H_ + h];
}

// ---------------------------------------------------------------------------
// Generic M=64 GEMM: C[m][n] = sum_k A[m][k] * W[n][k]  (+bias, opt tanh)
// Tile: 64x64, KT=32, 256 threads, 4x4 micro-tile per thread.
// Dual mode: global col n >= Nhalf uses A1/W1 with col offset -Nhalf.
// K-split: gridDim.y chunks; if Cpart != nullptr write raw partials
// Cpart[kc][m][n] (no bias), else direct write with bias/epilogue.
__global__ __launch_bounds__(256) void gemm_m64(
    const float* __restrict__ A0, const float* __restrict__ A1, int lda,
    const float* __restrict__ W0, const float* __restrict__ W1, int ldw,
    int Nhalf,
    const float* __restrict__ bias, float* __restrict__ C,
    float* __restrict__ Cpart, int ldc, int N, int K, int epi) {
    __shared__ float As[32][68];
    __shared__ float Ws[32][68];

    int n0 = blockIdx.x * 64;
    const float* A = A0;
    const float* W = W0;
    int ncol0 = n0;
    if (n0 >= Nhalf) { A = A1; W = W1; ncol0 = n0 - Nhalf; }

    int tid = threadIdx.x;
    int tx = tid & 15, ty = tid >> 4;
    int row = tid >> 3;   // 0..31
    int cg = tid & 7;     // 0..7  (k group of 4)

    float acc[4][4] = {};

    int kChunk = K / gridDim.y;
    int k0b = blockIdx.y * kChunk;

    for (int k0 = k0b; k0 < k0b + kChunk; k0 += 32) {
        // A tile: rows row, row+32 ; store transposed As[kk][m]
        {
            float4 a0 = *(const float4*)&A[(size_t)row * lda + k0 + cg * 4];
            float4 a1 = *(const float4*)&A[(size_t)(row + 32) * lda + k0 + cg * 4];
            As[cg * 4 + 0][row] = a0.x; As[cg * 4 + 1][row] = a0.y;
            As[cg * 4 + 2][row] = a0.z; As[cg * 4 + 3][row] = a0.w;
            As[cg * 4 + 0][row + 32] = a1.x; As[cg * 4 + 1][row + 32] = a1.y;
            As[cg * 4 + 2][row + 32] = a1.z; As[cg * 4 + 3][row + 32] = a1.w;
        }
        // W tile: W rows (output cols) ncol0+row, ncol0+row+32
        {
            bool v0 = (n0 + row) < N;
            bool v1 = (n0 + row + 32) < N;
            float4 w0 = v0 ? *(const float4*)&W[(size_t)(ncol0 + row) * ldw + k0 + cg * 4]
                           : float4{0.f, 0.f, 0.f, 0.f};
            float4 w1 = v1 ? *(const float4*)&W[(size_t)(ncol0 + row + 32) * ldw + k0 + cg * 4]
                           : float4{0.f, 0.f, 0.f, 0.f};
            Ws[cg * 4 + 0][row] = w0.x; Ws[cg * 4 + 1][row] = w0.y;
            Ws[cg * 4 + 2][row] = w0.z; Ws[cg * 4 + 3][row] = w0.w;
            Ws[cg * 4 + 0][row + 32] = w1.x; Ws[cg * 4 + 1][row + 32] = w1.y;
            Ws[cg * 4 + 2][row + 32] = w1.z; Ws[cg * 4 + 3][row + 32] = w1.w;
        }
        __syncthreads();
#pragma unroll
        for (int kk = 0; kk < 32; kk++) {
            float4 av = *(const float4*)&As[kk][ty * 4];
            float4 wv = *(const float4*)&Ws[kk][tx * 4];
            acc[0][0] += av.x * wv.x; acc[0][1] += av.x * wv.y;
            acc[0][2] += av.x * wv.z; acc[0][3] += av.x * wv.w;
            acc[1][0] += av.y * wv.x; acc[1][1] += av.y * wv.y;
            acc[1][2] += av.y * wv.z; acc[1][3] += av.y * wv.w;
            acc[2][0] += av.z * wv.x; acc[2][1] += av.z * wv.y;
            acc[2][2] += av.z * wv.z; acc[2][3] += av.z * wv.w;
            acc[3][0] += av.w * wv.x; acc[3][1] += av.w * wv.y;
            acc[3][2] += av.w * wv.z; acc[3][3] += av.w * wv.w;
        }
        __syncthreads();
    }

    if (Cpart) {
        float* P = Cpart + (size_t)blockIdx.y * 64 * N;
#pragma unroll
        for (int i = 0; i < 4; i++) {
            int m = ty * 4 + i;
#pragma unroll
            for (int j = 0; j < 4; j++) {
                int n = n0 + tx * 4 + j;
                if (n < N) P[(size_t)m * N + n] = acc[i][j];
            }
        }
    } else {
#pragma unroll
        for (int i = 0; i < 4; i++) {
            int m = ty * 4 + i;
#pragma unroll
            for (int j = 0; j < 4; j++) {
                int n = n0 + tx * 4 + j;
                if (n < N) {
                    float v = acc[i][j] + (bias ? bias[n] : 0.f);
                    if (epi == 1) v = tanhf(v);
                    C[(size_t)m * ldc + n] = v;
                }
            }
        }
    }
}

// ---------------------------------------------------------------------------
// GRU gate combine: reads 4 K-split partials of fused [gi | gh] (N=6144),
// adds biases, computes gate math, writes new hidden state.
__global__ __launch_bounds__(256) void gru_combine_k(
    const float* __restrict__ P, const float* __restrict__ b_ih,
    const float* __restrict__ b_hh, const float* __restrict__ hprev,
    float* __restrict__ hout) {
    int idx = blockIdx.x * 256 + threadIdx.x;  // 65536
    int b = idx >> 10, j = idx & 1023;
    const size_t stride = (size_t)64 * N_GATES;
    const float* rowp = P + (size_t)b * N_GATES;

    float ir = 0.f, iz = 0.f, in_ = 0.f, hr = 0.f, hz = 0.f, hn = 0.f;
#pragma unroll
    for (int kc = 0; kc < 4; kc++) {
        const float* p = rowp + kc * stride;
        ir += p[j];           iz += p[j + 1024];        in_ += p[j + 2048];
        hr += p[3072 + j];    hz += p[3072 + j + 1024]; hn += p[3072 + j + 2048];
    }
    ir += b_ih[j]; iz += b_ih[j + 1024]; in_ += b_ih[j + 2048];
    hr += b_hh[j]; hz += b_hh[j + 1024]; hn += b_hh[j + 2048];

    float r = 1.f / (1.f + expf(-(ir + hr)));
    float z = 1.f / (1.f + expf(-(iz + hz)));
    float n = tanhf(in_ + r * hn);
    float hp = hprev[idx];
    hout[idx] = (1.f - z) * n + z * hp;
}

// ---------------------------------------------------------------------------
// Attention scores: one wave per (b,s): scores[b][s] = rnn[b]·enc[s][b]
__global__ __launch_bounds__(256) void scores_k(const float* __restrict__ rnn,
                                                const float* __restrict__ enc,
                                                float* __restrict__ scores) {
    int gtid = blockIdx.x * 256 + threadIdx.x;
    int w = gtid >> 6, lane = gtid & 63;
    int b = w >> 10, s = w & 1023;
    const float4* er = (const float4*)(enc + ((size_t)s * B_ + b) * H_);
    const float4* rr = (const float4*)(rnn + (size_t)b * H_);
    float acc = 0.f;
#pragma unroll
    for (int i = 0; i < 4; i++) {
        float4 e = er[i * 64 + lane];
        float4 r = rr[i * 64 + lane];
        acc += e.x * r.x + e.y * r.y + e.z * r.z + e.w * r.w;
    }
#pragma unroll
    for (int off = 32; off; off >>= 1) acc += __shfl_down(acc, off, 64);
    if (lane == 0) scores[(size_t)b * S_ + s] = acc;
}

// ---------------------------------------------------------------------------
// Softmax over S=1024 per batch row; writes attn to d_out attn region.
__global__ __launch_bounds__(256) void softmax_k(const float* __restrict__ scores,
                                                 float* __restrict__ attn) {
    __shared__ float red[256];
    int b = blockIdx.x, tid = threadIdx.x;
    float v[4];
#pragma unroll
    for (int q = 0; q < 4; q++) v[q] = scores[(size_t)b * S_ + q * 256 + tid];
    float m = fmaxf(fmaxf(v[0], v[1]), fmaxf(v[2], v[3]));
    red[tid] = m; __syncthreads();
    for (int s = 128; s; s >>= 1) {
        if (tid < s) red[tid] = fmaxf(red[tid], red[tid + s]);
        __syncthreads();
    }
    float M = red[0]; __syncthreads();
    float e[4], sum = 0.f;
#pragma unroll
    for (int q = 0; q < 4; q++) { e[q] = expf(v[q] - M); sum += e[q]; }
    red[tid] = sum; __syncthreads();
    for (int s = 128; s; s >>= 1) {
        if (tid < s) red[tid] += red[tid + s];
        __syncthreads();
    }
    float inv = 1.f / red[0];
#pragma unroll
    for (int q = 0; q < 4; q++) attn[(size_t)b * S_ + q * 256 + tid] = e[q] * inv;
}

// ---------------------------------------------------------------------------
// Context partials: grid = (b, htile, schunk) = 64*4*4 = 1024 blocks.
// ctxPart[b][sc][h] = sum_{s in chunk} attn[b][s] * enc[s][b][h]
__global__ __launch_bounds__(256) void context_k(const float* __restrict__ attn,
                                                 const float* __restrict__ enc,
                                                 float* __restrict__ ctxPart) {
    __shared__ float aw[256];
    int bid = blockIdx.x;
    int b = bid >> 4, ht = (bid >> 2) & 3, sc = bid & 3;
    int tid = threadIdx.x;
    aw[tid] = attn[(size_t)b * S_ + sc * 256 + tid];
    __syncthreads();
    int h = ht * 256 + tid;
    const float* base = enc + ((size_t)(sc * 256) * B_ + b) * H_ + h;
    float acc = 0.f;
#pragma unroll 8
    for (int s = 0; s < 256; s++) acc += aw[s] * base[(size_t)s * (B_ * H_)];
    ctxPart[((size_t)b * 4 + sc) * H_ + h] = acc;
}

// ---------------------------------------------------------------------------
// Assemble concat input: [rnn | sum of ctx partials]
__global__ __launch_bounds__(256) void assemble_k(const float* __restrict__ rnn,
                                                  const float* __restrict__ ctxPart,
                                                  float* __restrict__ concat_in) {
    int idx = blockIdx.x * 256 + threadIdx.x;  // 65536
    int b = idx >> 10, h = idx & 1023;
    concat_in[(size_t)b * 2048 + h] = rnn[idx];
    float c = ctxPart[((size_t)b * 4 + 0) * H_ + h] + ctxPart[((size_t)b * 4 + 1) * H_ + h] +
              ctxPart[((size_t)b * 4 + 2) * H_ + h] + ctxPart[((size_t)b * 4 + 3) * H_ + h];
    concat_in[(size_t)b * 2048 + 1024 + h] = c;
}

// ---------------------------------------------------------------------------
// Concat combine: sum 8 K-split partials + bias, tanh.
__global__ __launch_bounds__(256) void concat_combine_k(const float* __restrict__ P,
                                                        const float* __restrict__ bias,
                                                        float* __restrict__ out) {
    int idx = blockIdx.x * 256 + threadIdx.x;  // 65536
    int b = idx >> 10, h = idx & 1023;
    float s = 0.f;
#pragma unroll
    for (int kc = 0; kc < 8; kc++) s += P[(size_t)kc * 65536 + (size_t)b * H_ + h];
    out[idx] = tanhf(s + bias[h]);
}

// ---------------------------------------------------------------------------
extern "C" void kernel_launch(void* const* d_in, const int* in_sizes, int n_in,
                              void* d_out, int out_size, void* d_ws, size_t ws_size,
                              hipStream_t stream) {
    const int* seq = (const int*)d_in[0];
    const float* last_hidden = (const float*)d_in[1];
    const float* enc = (const float*)d_in[2];
    const float* emb = (const float*)d_in[3];
    const float* w_ih = (const float*)d_in[4];
    const float* w_hh = (const float*)d_in[5];
    const float* b_ih = (const float*)d_in[6];
    const float* b_hh = (const float*)d_in[7];
    const float* concat_w = (const float*)d_in[8];
    const float* concat_b = (const float*)d_in[9];
    const float* out_w = (const float*)d_in[10];
    const float* out_b = (const float*)d_in[11];

    float* out = (float*)d_out;                       // (B,V)
    float* out_hidden = out + (size_t)B_ * V_;        // (L,B,H)
    float* out_attn = out_hidden + (size_t)L_ * B_ * H_;  // (B,1,S)

    float* ws = (float*)d_ws;
    float* x0 = ws;                         // 65536
    float* gatesP = x0 + 65536;             // 4*64*6144 = 1572864
    float* scores = gatesP + 1572864;       // 65536
    float* ctxPart = scores + 65536;        // 262144
    float* concat_in = ctxPart + 262144;    // 131072
    float* concatP = concat_in + 131072;    // 8*64*1024 = 524288
    float* concat_out = concatP + 524288;   // 65536

    // 1. Embedding
    embed_k<<<256, 256, 0, stream>>>(seq, emb, x0);

    // 2. GRU layers
    for (int l = 0; l < L_; l++) {
        const float* xl = (l == 0) ? x0 : out_hidden + (size_t)(l - 1) * B_ * H_;
        const float* hl = last_hidden + (size_t)l * B_ * H_;
        gemm_m64<<<dim3(N_GATES / 64, 4), 256, 0, stream>>>(
            xl, hl, H_,
            w_ih + (size_t)l * G3H * H_, w_hh + (size_t)l * G3H * H_, H_, G3H,
            nullptr, nullptr, gatesP, 0, N_GATES, H_, 0);
        gru_combine_k<<<256, 256, 0, stream>>>(gatesP, b_ih + (size_t)l * G3H,
                                               b_hh + (size_t)l * G3H, hl,
                                               out_hidden + (size_t)l * B_ * H_);
    }
    const float* rnn = out_hidden + (size_t)2 * B_ * H_;

    // 3. Attention
    scores_k<<<16384, 256, 0, stream>>>(rnn, enc, scores);
    softmax_k<<<64, 256, 0, stream>>>(scores, out_attn);
    context_k<<<1024, 256, 0, stream>>>(out_attn, enc, ctxPart);
    assemble_k<<<256, 256, 0, stream>>>(rnn, ctxPart, concat_in);

    // 4. Concat GEMM (K=2048, 8-way K-split) + tanh combine
    gemm_m64<<<dim3(16, 8), 256, 0, stream>>>(
        concat_in, concat_in, 2048, concat_w, concat_w, 2048, 1 << 30,
        nullptr, nullptr, concatP, 0, H_, 2048, 0);
    concat_combine_k<<<256, 256, 0, stream>>>(concatP, concat_b, concat_out);

    // 5. Output GEMM (direct, bias)
    gemm_m64<<<dim3((V_ + 63) / 64, 1), 256, 0, stream>>>(
        concat_out, concat_out, H_, out_w, out_w, H_, 1 << 30,
        out_b, out, nullptr, V_, V_, H_, 0);
}

// Round 2
// 328.933 us; speedup vs baseline: 1.0163x; 1.0163x over previous
//
#include <hip/hip_runtime.h>
#include <hip/hip_bf16.h>
#include <float.h>

#define B_ 64
#define H_ 1024
#define S_ 1024
#define V_ 50257
#define L_ 3
#define G3H 3072      // 3*H
#define N_GATES 6144  // 2*3H fused gi|gh

// ---------------------------------------------------------------------------
// Embedding gather: x0[b][h] = emb[seq[b]][h]
__global__ __launch_bounds__(256) void embed_k(const int* __restrict__ seq,
                                               const float* __restrict__ emb,
                                               float* __restrict__ x0) {
    int idx = blockIdx.x * 256 + threadIdx.x;  // 65536 total
    int b = idx >> 10, h = idx & 1023;
    x0[idx] = emb[(size_t)seq[b] * H_ + h];
}

// ---------------------------------------------------------------------------
// Generic M=64 GEMM (used for GRU gates + concat): C[m][n] = sum_k A[m][k]*W[n][k]
// Tile 64x64, KT=32, 256 threads, 4x4 micro-tile. Dual-A/W for fused gi|gh.
// K-split partials to Cpart[kc][m][n].
__global__ __launch_bounds__(256) void gemm_m64(
    const float* __restrict__ A0, const float* __restrict__ A1, int lda,
    const float* __restrict__ W0, const float* __restrict__ W1, int ldw,
    int Nhalf, float* __restrict__ Cpart, int N, int K) {
    __shared__ float As[32][68];
    __shared__ float Ws[32][68];

    int n0 = blockIdx.x * 64;
    const float* A = A0;
    const float* W = W0;
    int ncol0 = n0;
    if (n0 >= Nhalf) { A = A1; W = W1; ncol0 = n0 - Nhalf; }

    int tid = threadIdx.x;
    int tx = tid & 15, ty = tid >> 4;
    int row = tid >> 3;  // 0..31
    int cg = tid & 7;    // k group of 4

    float acc[4][4] = {};

    int kChunk = K / gridDim.y;
    int k0b = blockIdx.y * kChunk;

    for (int k0 = k0b; k0 < k0b + kChunk; k0 += 32) {
        {
            float4 a0 = *(const float4*)&A[(size_t)row * lda + k0 + cg * 4];
            float4 a1 = *(const float4*)&A[(size_t)(row + 32) * lda + k0 + cg * 4];
            As[cg * 4 + 0][row] = a0.x; As[cg * 4 + 1][row] = a0.y;
            As[cg * 4 + 2][row] = a0.z; As[cg * 4 + 3][row] = a0.w;
            As[cg * 4 + 0][row + 32] = a1.x; As[cg * 4 + 1][row + 32] = a1.y;
            As[cg * 4 + 2][row + 32] = a1.z; As[cg * 4 + 3][row + 32] = a1.w;
        }
        {
            float4 w0 = *(const float4*)&W[(size_t)(ncol0 + row) * ldw + k0 + cg * 4];
            float4 w1 = *(const float4*)&W[(size_t)(ncol0 + row + 32) * ldw + k0 + cg * 4];
            Ws[cg * 4 + 0][row] = w0.x; Ws[cg * 4 + 1][row] = w0.y;
            Ws[cg * 4 + 2][row] = w0.z; Ws[cg * 4 + 3][row] = w0.w;
            Ws[cg * 4 + 0][row + 32] = w1.x; Ws[cg * 4 + 1][row + 32] = w1.y;
            Ws[cg * 4 + 2][row + 32] = w1.z; Ws[cg * 4 + 3][row + 32] = w1.w;
        }
        __syncthreads();
#pragma unroll
        for (int kk = 0; kk < 32; kk++) {
            float4 av = *(const float4*)&As[kk][ty * 4];
            float4 wv = *(const float4*)&Ws[kk][tx * 4];
            acc[0][0] += av.x * wv.x; acc[0][1] += av.x * wv.y;
            acc[0][2] += av.x * wv.z; acc[0][3] += av.x * wv.w;
            acc[1][0] += av.y * wv.x; acc[1][1] += av.y * wv.y;
            acc[1][2] += av.y * wv.z; acc[1][3] += av.y * wv.w;
            acc[2][0] += av.z * wv.x; acc[2][1] += av.z * wv.y;
            acc[2][2] += av.z * wv.z; acc[2][3] += av.z * wv.w;
            acc[3][0] += av.w * wv.x; acc[3][1] += av.w * wv.y;
            acc[3][2] += av.w * wv.z; acc[3][3] += av.w * wv.w;
        }
        __syncthreads();
    }

    float* P = Cpart + (size_t)blockIdx.y * 64 * N;
#pragma unroll
    for (int i = 0; i < 4; i++) {
        int m = ty * 4 + i;
#pragma unroll
        for (int j = 0; j < 4; j++) {
            int n = n0 + tx * 4 + j;
            P[(size_t)m * N + n] = acc[i][j];
        }
    }
}

// ---------------------------------------------------------------------------
// GRU gate combine: 4 K-split partials of fused [gi | gh] + biases -> h_out
__global__ __launch_bounds__(256) void gru_combine_k(
    const float* __restrict__ P, const float* __restrict__ b_ih,
    const float* __restrict__ b_hh, const float* __restrict__ hprev,
    float* __restrict__ hout) {
    int idx = blockIdx.x * 256 + threadIdx.x;  // 65536
    int b = idx >> 10, j = idx & 1023;
    const size_t stride = (size_t)64 * N_GATES;
    const float* rowp = P + (size_t)b * N_GATES;

    float ir = 0.f, iz = 0.f, in_ = 0.f, hr = 0.f, hz = 0.f, hn = 0.f;
#pragma unroll
    for (int kc = 0; kc < 4; kc++) {
        const float* p = rowp + kc * stride;
        ir += p[j];        iz += p[j + 1024];        in_ += p[j + 2048];
        hr += p[3072 + j]; hz += p[3072 + j + 1024]; hn += p[3072 + j + 2048];
    }
    ir += b_ih[j]; iz += b_ih[j + 1024]; in_ += b_ih[j + 2048];
    hr += b_hh[j]; hz += b_hh[j + 1024]; hn += b_hh[j + 2048];

    float r = 1.f / (1.f + __expf(-(ir + hr)));
    float z = 1.f / (1.f + __expf(-(iz + hz)));
    float n = tanhf(in_ + r * hn);
    float hp = hprev[idx];
    hout[idx] = (1.f - z) * n + z * hp;
}

// ---------------------------------------------------------------------------
// Fused attention pass 1: one enc read produces BOTH raw scores and
// online-softmax-weighted context partials.
// grid = 64 b * 16 sc = 1024 blocks; 4 waves/block, each wave owns 16 s rows.
// Each lane holds rnn/enc h-slices {i*256 + lane*4 .. +3}, i=0..3.
__global__ __launch_bounds__(256) void attn_pass1(
    const float* __restrict__ rnn, const float* __restrict__ enc,
    float* __restrict__ scores, float* __restrict__ ctxPart,
    float* __restrict__ chunkMax) {
    __shared__ float lm[4];
    __shared__ float lc[4][1024];  // 16 KB wave partial contexts

    int bid = blockIdx.x;
    int b = bid >> 4, scv = bid & 15;
    int tid = threadIdx.x;
    int w = tid >> 6, lane = tid & 63;

    const float4* rr = (const float4*)(rnn + (size_t)b * H_);
    float4 r0 = rr[0 * 64 + lane], r1 = rr[1 * 64 + lane];
    float4 r2 = rr[2 * 64 + lane], r3 = rr[3 * 64 + lane];

    float m = -FLT_MAX;
    float4 c0 = {0, 0, 0, 0}, c1 = {0, 0, 0, 0}, c2 = {0, 0, 0, 0}, c3 = {0, 0, 0, 0};

    int s0 = scv * 64 + w * 16;
    for (int si = 0; si < 16; si++) {
        int s = s0 + si;
        const float4* er = (const float4*)(enc + ((size_t)s * B_ + b) * H_);
        float4 e0 = er[0 * 64 + lane], e1 = er[1 * 64 + lane];
        float4 e2 = er[2 * 64 + lane], e3 = er[3 * 64 + lane];

        float d = e0.x * r0.x + e0.y * r0.y + e0.z * r0.z + e0.w * r0.w;
        d += e1.x * r1.x + e1.y * r1.y + e1.z * r1.z + e1.w * r1.w;
        d += e2.x * r2.x + e2.y * r2.y + e2.z * r2.z + e2.w * r2.w;
        d += e3.x * r3.x + e3.y * r3.y + e3.z * r3.z + e3.w * r3.w;
#pragma unroll
        for (int off = 32; off; off >>= 1) d += __shfl_xor(d, off, 64);
        if (lane == 0) scores[(size_t)b * S_ + s] = d;

        if (d > m) {  // wave-uniform branch (d identical on all lanes)
            float scale = __expf(m - d);  // first iter: exp(-inf) = 0
            c0.x *= scale; c0.y *= scale; c0.z *= scale; c0.w *= scale;
            c1.x *= scale; c1.y *= scale; c1.z *= scale; c1.w *= scale;
            c2.x *= scale; c2.y *= scale; c2.z *= scale; c2.w *= scale;
            c3.x *= scale; c3.y *= scale; c3.z *= scale; c3.w *= scale;
            m = d;
        }
        float p = __expf(d - m);
        c0.x += p * e0.x; c0.y += p * e0.y; c0.z += p * e0.z; c0.w += p * e0.w;
        c1.x += p * e1.x; c1.y += p * e1.y; c1.z += p * e1.z; c1.w += p * e1.w;
        c2.x += p * e2.x; c2.y += p * e2.y; c2.z += p * e2.z; c2.w += p * e2.w;
        c3.x += p * e3.x; c3.y += p * e3.y; c3.z += p * e3.z; c3.w += p * e3.w;
    }

    // merge 4 waves: common max, rescale, sum via LDS
    if (lane == 0) lm[w] = m;
    __syncthreads();
    float M = fmaxf(fmaxf(lm[0], lm[1]), fmaxf(lm[2], lm[3]));
    float sw = __expf(m - M);
    float4* lw = (float4*)&lc[w][0];
    float4 t;
    t.x = c0.x * sw; t.y = c0.y * sw; t.z = c0.z * sw; t.w = c0.w * sw; lw[0 * 64 + lane] = t;
    t.x = c1.x * sw; t.y = c1.y * sw; t.z = c1.z * sw; t.w = c1.w * sw; lw[1 * 64 + lane] = t;
    t.x = c2.x * sw; t.y = c2.y * sw; t.z = c2.z * sw; t.w = c2.w * sw; lw[2 * 64 + lane] = t;
    t.x = c3.x * sw; t.y = c3.y * sw; t.z = c3.z * sw; t.w = c3.w * sw; lw[3 * 64 + lane] = t;
    __syncthreads();

    float4 s4 = *(const float4*)&lc[0][tid * 4];
    float4 a1 = *(const float4*)&lc[1][tid * 4];
    float4 a2 = *(const float4*)&lc[2][tid * 4];
    float4 a3 = *(const float4*)&lc[3][tid * 4];
    s4.x += a1.x + a2.x + a3.x; s4.y += a1.y + a2.y + a3.y;
    s4.z += a1.z + a2.z + a3.z; s4.w += a1.w + a2.w + a3.w;
    *(float4*)&ctxPart[(size_t)bid * H_ + tid * 4] = s4;
    if (tid == 0) chunkMax[bid] = M;
}

// ---------------------------------------------------------------------------
// Attention pass 2 (per b): global softmax from stored scores -> attn output,
// rescale+sum the 16 chunk context partials, assemble concat_in = [rnn | ctx].
__global__ __launch_bounds__(256) void attn_pass2(
    const float* __restrict__ scores, const float* __restrict__ chunkMax,
    const float* __restrict__ ctxPart, const float* __restrict__ rnn,
    float* __restrict__ attn, float* __restrict__ concat_in) {
    __shared__ float red[256];
    int b = blockIdx.x, tid = threadIdx.x;

    float v[4];
#pragma unroll
    for (int q = 0; q < 4; q++) v[q] = scores[(size_t)b * S_ + q * 256 + tid];
    float mx = fmaxf(fmaxf(v[0], v[1]), fmaxf(v[2], v[3]));
    red[tid] = mx; __syncthreads();
    for (int s = 128; s; s >>= 1) {
        if (tid < s) red[tid] = fmaxf(red[tid], red[tid + s]);
        __syncthreads();
    }
    float M = red[0]; __syncthreads();
    float e[4], sum = 0.f;
#pragma unroll
    for (int q = 0; q < 4; q++) { e[q] = __expf(v[q] - M); sum += e[q]; }
    red[tid] = sum; __syncthreads();
    for (int s = 128; s; s >>= 1) {
        if (tid < s) red[tid] += red[tid + s];
        __syncthreads();
    }
    float inv = 1.f / red[0];
#pragma unroll
    for (int q = 0; q < 4; q++) attn[(size_t)b * S_ + q * 256 + tid] = e[q] * inv;

    // context: thread owns h = tid*4 .. +3
    float4 acc = {0, 0, 0, 0};
#pragma unroll
    for (int c = 0; c < 16; c++) {
        float scl = __expf(chunkMax[b * 16 + c] - M);
        float4 part = *(const float4*)&ctxPart[((size_t)b * 16 + c) * H_ + tid * 4];
        acc.x += scl * part.x; acc.y += scl * part.y;
        acc.z += scl * part.z; acc.w += scl * part.w;
    }
    acc.x *= inv; acc.y *= inv; acc.z *= inv; acc.w *= inv;
    *(float4*)&concat_in[(size_t)b * 2048 + 1024 + tid * 4] = acc;
    *(float4*)&concat_in[(size_t)b * 2048 + tid * 4] =
        *(const float4*)&rnn[(size_t)b * H_ + tid * 4];
}

// ---------------------------------------------------------------------------
// Concat combine: sum 8 K-split partials + bias, tanh.
__global__ __launch_bounds__(256) void concat_combine_k(const float* __restrict__ P,
                                                        const float* __restrict__ bias,
                                                        float* __restrict__ out) {
    int idx = blockIdx.x * 256 + threadIdx.x;  // 65536
    int b = idx >> 10, h = idx & 1023;
    float s = 0.f;
#pragma unroll
    for (int kc = 0; kc < 8; kc++) s += P[(size_t)kc * 65536 + (size_t)b * H_ + h];
    out[idx] = tanhf(s + bias[h]);
}

// ---------------------------------------------------------------------------
// Output GEMM: C[64][V] = A[64][1024] * W[V][1024]^T + bias.
// Tile 64(M) x 128(N), KT=32, 256 threads, 4x8 micro-tile.
__global__ __launch_bounds__(256) void gemm_out_k(const float* __restrict__ A,
                                                  const float* __restrict__ W,
                                                  const float* __restrict__ bias,
                                                  float* __restrict__ C) {
    __shared__ float As[32][68];
    __shared__ float Ws[32][132];

    int n0 = blockIdx.x * 128;
    int tid = threadIdx.x;
    int tx = tid & 15, ty = tid >> 4;
    int row = tid >> 3;  // 0..31
    int cg = tid & 7;

    float acc[4][8] = {};

    for (int k0 = 0; k0 < H_; k0 += 32) {
        {
            float4 a0 = *(const float4*)&A[(size_t)row * H_ + k0 + cg * 4];
            float4 a1 = *(const float4*)&A[(size_t)(row + 32) * H_ + k0 + cg * 4];
            As[cg * 4 + 0][row] = a0.x; As[cg * 4 + 1][row] = a0.y;
            As[cg * 4 + 2][row] = a0.z; As[cg * 4 + 3][row] = a0.w;
            As[cg * 4 + 0][row + 32] = a1.x; As[cg * 4 + 1][row + 32] = a1.y;
            As[cg * 4 + 2][row + 32] = a1.z; As[cg * 4 + 3][row + 32] = a1.w;
        }
#pragma unroll
        for (int q = 0; q < 4; q++) {
            int nr = n0 + row + q * 32;
            float4 wv = (nr < V_) ? *(const float4*)&W[(size_t)nr * H_ + k0 + cg * 4]
                                  : float4{0.f, 0.f, 0.f, 0.f};
            Ws[cg * 4 + 0][row + q * 32] = wv.x; Ws[cg * 4 + 1][row + q * 32] = wv.y;
            Ws[cg * 4 + 2][row + q * 32] = wv.z; Ws[cg * 4 + 3][row + q * 32] = wv.w;
        }
        __syncthreads();
#pragma unroll
        for (int kk = 0; kk < 32; kk++) {
            float4 av = *(const float4*)&As[kk][ty * 4];
            float4 w0 = *(const float4*)&Ws[kk][tx * 8];
            float4 w1 = *(const float4*)&Ws[kk][tx * 8 + 4];
            float a0 = av.x, a1 = av.y, a2 = av.z, a3 = av.w;
            acc[0][0] += a0 * w0.x; acc[0][1] += a0 * w0.y; acc[0][2] += a0 * w0.z; acc[0][3] += a0 * w0.w;
            acc[0][4] += a0 * w1.x; acc[0][5] += a0 * w1.y; acc[0][6] += a0 * w1.z; acc[0][7] += a0 * w1.w;
            acc[1][0] += a1 * w0.x; acc[1][1] += a1 * w0.y; acc[1][2] += a1 * w0.z; acc[1][3] += a1 * w0.w;
            acc[1][4] += a1 * w1.x; acc[1][5] += a1 * w1.y; acc[1][6] += a1 * w1.z; acc[1][7] += a1 * w1.w;
            acc[2][0] += a2 * w0.x; acc[2][1] += a2 * w0.y; acc[2][2] += a2 * w0.z; acc[2][3] += a2 * w0.w;
            acc[2][4] += a2 * w1.x; acc[2][5] += a2 * w1.y; acc[2][6] += a2 * w1.z; acc[2][7] += a2 * w1.w;
            acc[3][0] += a3 * w0.x; acc[3][1] += a3 * w0.y; acc[3][2] += a3 * w0.z; acc[3][3] += a3 * w0.w;
            acc[3][4] += a3 * w1.x; acc[3][5] += a3 * w1.y; acc[3][6] += a3 * w1.z; acc[3][7] += a3 * w1.w;
        }
        __syncthreads();
    }

#pragma unroll
    for (int i = 0; i < 4; i++) {
        int mrow = ty * 4 + i;
#pragma unroll
        for (int j = 0; j < 8; j++) {
            int n = n0 + tx * 8 + j;
            if (n < V_) C[(size_t)mrow * V_ + n] = acc[i][j] + bias[n];
        }
    }
}

// ---------------------------------------------------------------------------
extern "C" void kernel_launch(void* const* d_in, const int* in_sizes, int n_in,
                              void* d_out, int out_size, void* d_ws, size_t ws_size,
                              hipStream_t stream) {
    const int* seq = (const int*)d_in[0];
    const float* last_hidden = (const float*)d_in[1];
    const float* enc = (const float*)d_in[2];
    const float* emb = (const float*)d_in[3];
    const float* w_ih = (const float*)d_in[4];
    const float* w_hh = (const float*)d_in[5];
    const float* b_ih = (const float*)d_in[6];
    const float* b_hh = (const float*)d_in[7];
    const float* concat_w = (const float*)d_in[8];
    const float* concat_b = (const float*)d_in[9];
    const float* out_w = (const float*)d_in[10];
    const float* out_b = (const float*)d_in[11];

    float* out = (float*)d_out;                           // (B,V)
    float* out_hidden = out + (size_t)B_ * V_;            // (L,B,H)
    float* out_attn = out_hidden + (size_t)L_ * B_ * H_;  // (B,1,S)

    float* ws = (float*)d_ws;
    float* x0 = ws;                        // 65536
    float* gatesP = x0 + 65536;            // 4*64*6144 = 1572864
    float* scores = gatesP + 1572864;      // 65536
    float* chunkMax = scores + 65536;      // 1024
    float* ctxPart = chunkMax + 1024;      // 1024*1024 = 1048576
    float* concat_in = ctxPart + 1048576;  // 131072
    float* concatP = concat_in + 131072;   // 8*64*1024 = 524288
    float* concat_out = concatP + 524288;  // 65536

    // 1. Embedding
    embed_k<<<256, 256, 0, stream>>>(seq, emb, x0);

    // 2. GRU layers
    for (int l = 0; l < L_; l++) {
        const float* xl = (l == 0) ? x0 : out_hidden + (size_t)(l - 1) * B_ * H_;
        const float* hl = last_hidden + (size_t)l * B_ * H_;
        gemm_m64<<<dim3(N_GATES / 64, 4), 256, 0, stream>>>(
            xl, hl, H_,
            w_ih + (size_t)l * G3H * H_, w_hh + (size_t)l * G3H * H_, H_, G3H,
            gatesP, N_GATES, H_);
        gru_combine_k<<<256, 256, 0, stream>>>(gatesP, b_ih + (size_t)l * G3H,
                                               b_hh + (size_t)l * G3H, hl,
                                               out_hidden + (size_t)l * B_ * H_);
    }
    const float* rnn = out_hidden + (size_t)2 * B_ * H_;

    // 3. Fused attention (single enc pass) + combine/assemble
    attn_pass1<<<1024, 256, 0, stream>>>(rnn, enc, scores, ctxPart, chunkMax);
    attn_pass2<<<64, 256, 0, stream>>>(scores, chunkMax, ctxPart, rnn,
                                       out_attn, concat_in);

    // 4. Concat GEMM (K=2048, 8-way K-split) + tanh combine
    gemm_m64<<<dim3(16, 8), 256, 0, stream>>>(
        concat_in, concat_in, 2048, concat_w, concat_w, 2048, 1 << 30,
        concatP, H_, 2048);
    concat_combine_k<<<256, 256, 0, stream>>>(concatP, concat_b, concat_out);

    // 5. Output GEMM (direct, bias)
    gemm_out_k<<<(V_ + 127) / 128, 256, 0, stream>>>(concat_out, out_w, out_b, out);
}

// Round 3
// 286.626 us; speedup vs baseline: 1.1663x; 1.1476x over previous
//
#include <hip/hip_runtime.h>
#include <hip/hip_bf16.h>
#include <float.h>

#define B_ 64
#define H_ 1024
#define S_ 1024
#define V_ 50257
#define VPAD 50304   // V padded to multiple of 128
#define L_ 3
#define G3H 3072      // 3*H
#define N_GATES 6144  // 2*3H fused gi|gh

// LDS XOR swizzle: permute 16B chunks within a row by kk's chunk bits.
// Bijective (XOR of 3-bit value into chunk index); keeps 16B alignment.
__device__ __forceinline__ int swzi(int kk, int m) {
    return (((m >> 2) ^ ((kk >> 2) & 7)) << 2) | (m & 3);
}

// ---------------------------------------------------------------------------
// Embedding gather: x0[b][h] = emb[seq[b]][h]
__global__ __launch_bounds__(256) void embed_k(const int* __restrict__ seq,
                                               const float* __restrict__ emb,
                                               float* __restrict__ x0) {
    int idx = blockIdx.x * 256 + threadIdx.x;  // 65536 total
    int b = idx >> 10, h = idx & 1023;
    x0[idx] = emb[(size_t)seq[b] * H_ + h];
}

// ---------------------------------------------------------------------------
// Generic M=64 GEMM (GRU gates + concat): C[m][n] = sum_k A[m][k]*W[n][k]
// Tile 64x64, KT=32, 256 threads, 4x4 micro-tile, swizzled LDS.
// K-split partials to Cpart[kc][m][n].
__global__ __launch_bounds__(256) void gemm_m64(
    const float* __restrict__ A0, const float* __restrict__ A1, int lda,
    const float* __restrict__ W0, const float* __restrict__ W1, int ldw,
    int Nhalf, float* __restrict__ Cpart, int N, int K) {
    __shared__ float As[32 * 68];
    __shared__ float Ws[32 * 68];

    int n0 = blockIdx.x * 64;
    const float* A = A0;
    const float* W = W0;
    int ncol0 = n0;
    if (n0 >= Nhalf) { A = A1; W = W1; ncol0 = n0 - Nhalf; }

    int tid = threadIdx.x;
    int tx = tid & 15, ty = tid >> 4;
    int row = tid >> 3;  // 0..31
    int cg = tid & 7;    // k group of 4

    float acc[4][4] = {};

    int kChunk = K / gridDim.y;
    int k0b = blockIdx.y * kChunk;

    for (int k0 = k0b; k0 < k0b + kChunk; k0 += 32) {
        float4 a0 = *(const float4*)&A[(size_t)row * lda + k0 + cg * 4];
        float4 a1 = *(const float4*)&A[(size_t)(row + 32) * lda + k0 + cg * 4];
        float4 w0 = *(const float4*)&W[(size_t)(ncol0 + row) * ldw + k0 + cg * 4];
        float4 w1 = *(const float4*)&W[(size_t)(ncol0 + row + 32) * ldw + k0 + cg * 4];
        const float* fa0 = (const float*)&a0;
        const float* fa1 = (const float*)&a1;
        const float* fw0 = (const float*)&w0;
        const float* fw1 = (const float*)&w1;
#pragma unroll
        for (int j = 0; j < 4; j++) {
            int kk = cg * 4 + j;
            As[kk * 68 + swzi(kk, row)] = fa0[j];
            As[kk * 68 + swzi(kk, row + 32)] = fa1[j];
            Ws[kk * 68 + swzi(kk, row)] = fw0[j];
            Ws[kk * 68 + swzi(kk, row + 32)] = fw1[j];
        }
        __syncthreads();
#pragma unroll
        for (int kk = 0; kk < 32; kk++) {
            int cgk = (kk >> 2) & 7;
            float4 av = *(const float4*)&As[kk * 68 + ((ty ^ cgk) << 2)];
            float4 wv = *(const float4*)&Ws[kk * 68 + ((tx ^ cgk) << 2)];
            acc[0][0] += av.x * wv.x; acc[0][1] += av.x * wv.y;
            acc[0][2] += av.x * wv.z; acc[0][3] += av.x * wv.w;
            acc[1][0] += av.y * wv.x; acc[1][1] += av.y * wv.y;
            acc[1][2] += av.y * wv.z; acc[1][3] += av.y * wv.w;
            acc[2][0] += av.z * wv.x; acc[2][1] += av.z * wv.y;
            acc[2][2] += av.z * wv.z; acc[2][3] += av.z * wv.w;
            acc[3][0] += av.w * wv.x; acc[3][1] += av.w * wv.y;
            acc[3][2] += av.w * wv.z; acc[3][3] += av.w * wv.w;
        }
        __syncthreads();
    }

    float* P = Cpart + (size_t)blockIdx.y * 64 * N;
#pragma unroll
    for (int i = 0; i < 4; i++) {
        int m = ty * 4 + i;
#pragma unroll
        for (int j = 0; j < 4; j++) {
            int n = n0 + tx * 4 + j;
            P[(size_t)m * N + n] = acc[i][j];
        }
    }
}

// ---------------------------------------------------------------------------
// GRU gate combine: 4 K-split partials of fused [gi | gh] + biases -> h_out
__global__ __launch_bounds__(256) void gru_combine_k(
    const float* __restrict__ P, const float* __restrict__ b_ih,
    const float* __restrict__ b_hh, const float* __restrict__ hprev,
    float* __restrict__ hout) {
    int idx = blockIdx.x * 256 + threadIdx.x;  // 65536
    int b = idx >> 10, j = idx & 1023;
    const size_t stride = (size_t)64 * N_GATES;
    const float* rowp = P + (size_t)b * N_GATES;

    float ir = 0.f, iz = 0.f, in_ = 0.f, hr = 0.f, hz = 0.f, hn = 0.f;
#pragma unroll
    for (int kc = 0; kc < 4; kc++) {
        const float* p = rowp + kc * stride;
        ir += p[j];        iz += p[j + 1024];        in_ += p[j + 2048];
        hr += p[3072 + j]; hz += p[3072 + j + 1024]; hn += p[3072 + j + 2048];
    }
    ir += b_ih[j]; iz += b_ih[j + 1024]; in_ += b_ih[j + 2048];
    hr += b_hh[j]; hz += b_hh[j + 1024]; hn += b_hh[j + 2048];

    float r = 1.f / (1.f + __expf(-(ir + hr)));
    float z = 1.f / (1.f + __expf(-(iz + hz)));
    float n = tanhf(in_ + r * hn);
    float hp = hprev[idx];
    hout[idx] = (1.f - z) * n + z * hp;
}

// ---------------------------------------------------------------------------
// Fused attention pass 1: one enc read -> raw scores + online-softmax context
// partials. grid = 64 b * 16 sc; 4 waves/block, each wave owns 16 s rows.
__global__ __launch_bounds__(256) void attn_pass1(
    const float* __restrict__ rnn, const float* __restrict__ enc,
    float* __restrict__ scores, float* __restrict__ ctxPart,
    float* __restrict__ chunkMax) {
    __shared__ float lm[4];
    __shared__ float lc[4][1024];

    int bid = blockIdx.x;
    int b = bid >> 4, scv = bid & 15;
    int tid = threadIdx.x;
    int w = tid >> 6, lane = tid & 63;

    const float4* rr = (const float4*)(rnn + (size_t)b * H_);
    float4 r0 = rr[0 * 64 + lane], r1 = rr[1 * 64 + lane];
    float4 r2 = rr[2 * 64 + lane], r3 = rr[3 * 64 + lane];

    float m = -FLT_MAX;
    float4 c0 = {0, 0, 0, 0}, c1 = {0, 0, 0, 0}, c2 = {0, 0, 0, 0}, c3 = {0, 0, 0, 0};

    int s0 = scv * 64 + w * 16;
    for (int si = 0; si < 16; si++) {
        int s = s0 + si;
        const float4* er = (const float4*)(enc + ((size_t)s * B_ + b) * H_);
        float4 e0 = er[0 * 64 + lane], e1 = er[1 * 64 + lane];
        float4 e2 = er[2 * 64 + lane], e3 = er[3 * 64 + lane];

        float d = e0.x * r0.x + e0.y * r0.y + e0.z * r0.z + e0.w * r0.w;
        d += e1.x * r1.x + e1.y * r1.y + e1.z * r1.z + e1.w * r1.w;
        d += e2.x * r2.x + e2.y * r2.y + e2.z * r2.z + e2.w * r2.w;
        d += e3.x * r3.x + e3.y * r3.y + e3.z * r3.z + e3.w * r3.w;
#pragma unroll
        for (int off = 32; off; off >>= 1) d += __shfl_xor(d, off, 64);
        if (lane == 0) scores[(size_t)b * S_ + s] = d;

        if (d > m) {  // wave-uniform (d identical on all lanes)
            float scale = __expf(m - d);
            c0.x *= scale; c0.y *= scale; c0.z *= scale; c0.w *= scale;
            c1.x *= scale; c1.y *= scale; c1.z *= scale; c1.w *= scale;
            c2.x *= scale; c2.y *= scale; c2.z *= scale; c2.w *= scale;
            c3.x *= scale; c3.y *= scale; c3.z *= scale; c3.w *= scale;
            m = d;
        }
        float p = __expf(d - m);
        c0.x += p * e0.x; c0.y += p * e0.y; c0.z += p * e0.z; c0.w += p * e0.w;
        c1.x += p * e1.x; c1.y += p * e1.y; c1.z += p * e1.z; c1.w += p * e1.w;
        c2.x += p * e2.x; c2.y += p * e2.y; c2.z += p * e2.z; c2.w += p * e2.w;
        c3.x += p * e3.x; c3.y += p * e3.y; c3.z += p * e3.z; c3.w += p * e3.w;
    }

    if (lane == 0) lm[w] = m;
    __syncthreads();
    float M = fmaxf(fmaxf(lm[0], lm[1]), fmaxf(lm[2], lm[3]));
    float sw = __expf(m - M);
    float4* lw = (float4*)&lc[w][0];
    float4 t;
    t.x = c0.x * sw; t.y = c0.y * sw; t.z = c0.z * sw; t.w = c0.w * sw; lw[0 * 64 + lane] = t;
    t.x = c1.x * sw; t.y = c1.y * sw; t.z = c1.z * sw; t.w = c1.w * sw; lw[1 * 64 + lane] = t;
    t.x = c2.x * sw; t.y = c2.y * sw; t.z = c2.z * sw; t.w = c2.w * sw; lw[2 * 64 + lane] = t;
    t.x = c3.x * sw; t.y = c3.y * sw; t.z = c3.z * sw; t.w = c3.w * sw; lw[3 * 64 + lane] = t;
    __syncthreads();

    float4 s4 = *(const float4*)&lc[0][tid * 4];
    float4 a1 = *(const float4*)&lc[1][tid * 4];
    float4 a2 = *(const float4*)&lc[2][tid * 4];
    float4 a3 = *(const float4*)&lc[3][tid * 4];
    s4.x += a1.x + a2.x + a3.x; s4.y += a1.y + a2.y + a3.y;
    s4.z += a1.z + a2.z + a3.z; s4.w += a1.w + a2.w + a3.w;
    *(float4*)&ctxPart[(size_t)bid * H_ + tid * 4] = s4;
    if (tid == 0) chunkMax[bid] = M;
}

// ---------------------------------------------------------------------------
// Attention pass 2 (per b): global softmax -> attn output, rescale+sum chunk
// contexts, assemble concat_in = [rnn | ctx].
__global__ __launch_bounds__(256) void attn_pass2(
    const float* __restrict__ scores, const float* __restrict__ chunkMax,
    const float* __restrict__ ctxPart, const float* __restrict__ rnn,
    float* __restrict__ attn, float* __restrict__ concat_in) {
    __shared__ float red[256];
    int b = blockIdx.x, tid = threadIdx.x;

    float v[4];
#pragma unroll
    for (int q = 0; q < 4; q++) v[q] = scores[(size_t)b * S_ + q * 256 + tid];
    float mx = fmaxf(fmaxf(v[0], v[1]), fmaxf(v[2], v[3]));
    red[tid] = mx; __syncthreads();
    for (int s = 128; s; s >>= 1) {
        if (tid < s) red[tid] = fmaxf(red[tid], red[tid + s]);
        __syncthreads();
    }
    float M = red[0]; __syncthreads();
    float e[4], sum = 0.f;
#pragma unroll
    for (int q = 0; q < 4; q++) { e[q] = __expf(v[q] - M); sum += e[q]; }
    red[tid] = sum; __syncthreads();
    for (int s = 128; s; s >>= 1) {
        if (tid < s) red[tid] += red[tid + s];
        __syncthreads();
    }
    float inv = 1.f / red[0];
#pragma unroll
    for (int q = 0; q < 4; q++) attn[(size_t)b * S_ + q * 256 + tid] = e[q] * inv;

    float4 acc = {0, 0, 0, 0};
#pragma unroll
    for (int c = 0; c < 16; c++) {
        float scl = __expf(chunkMax[b * 16 + c] - M);
        float4 part = *(const float4*)&ctxPart[((size_t)b * 16 + c) * H_ + tid * 4];
        acc.x += scl * part.x; acc.y += scl * part.y;
        acc.z += scl * part.z; acc.w += scl * part.w;
    }
    acc.x *= inv; acc.y *= inv; acc.z *= inv; acc.w *= inv;
    *(float4*)&concat_in[(size_t)b * 2048 + 1024 + tid * 4] = acc;
    *(float4*)&concat_in[(size_t)b * 2048 + tid * 4] =
        *(const float4*)&rnn[(size_t)b * H_ + tid * 4];
}

// ---------------------------------------------------------------------------
// Concat combine: sum 8 K-split partials + bias, tanh.
__global__ __launch_bounds__(256) void concat_combine_k(const float* __restrict__ P,
                                                        const float* __restrict__ bias,
                                                        float* __restrict__ out) {
    int idx = blockIdx.x * 256 + threadIdx.x;  // 65536
    int b = idx >> 10, h = idx & 1023;
    float s = 0.f;
#pragma unroll
    for (int kc = 0; kc < 8; kc++) s += P[(size_t)kc * 65536 + (size_t)b * H_ + h];
    out[idx] = tanhf(s + bias[h]);
}

// ---------------------------------------------------------------------------
// Output GEMM: P[ks][64][VPAD] partials of A[64][1024] * W[V][1024]^T.
// Tile 64(M) x 128(N), KT=32, K-split 2, 256 threads, 4x8 micro-tile,
// swizzled LDS, register-pipelined staging.
__global__ __launch_bounds__(256) void gemm_out_k(const float* __restrict__ A,
                                                  const float* __restrict__ W,
                                                  float* __restrict__ P) {
    __shared__ float As[32 * 68];
    __shared__ float Ws[32 * 132];

    int n0 = blockIdx.x * 128;
    int ks = blockIdx.y;
    int tid = threadIdx.x;
    int tx = tid & 15, ty = tid >> 4;
    int row = tid >> 3;  // 0..31
    int cg = tid & 7;

    float acc[4][8] = {};
    float4 pa0, pa1, pw0, pw1, pw2, pw3;

    const int kBeg = ks * 512, kEnd = kBeg + 512;

    auto loadTile = [&](int k0) {
        pa0 = *(const float4*)&A[(size_t)row * H_ + k0 + cg * 4];
        pa1 = *(const float4*)&A[(size_t)(row + 32) * H_ + k0 + cg * 4];
        int nr;
        nr = n0 + row;
        pw0 = (nr < V_) ? *(const float4*)&W[(size_t)nr * H_ + k0 + cg * 4] : float4{0, 0, 0, 0};
        nr = n0 + row + 32;
        pw1 = (nr < V_) ? *(const float4*)&W[(size_t)nr * H_ + k0 + cg * 4] : float4{0, 0, 0, 0};
        nr = n0 + row + 64;
        pw2 = (nr < V_) ? *(const float4*)&W[(size_t)nr * H_ + k0 + cg * 4] : float4{0, 0, 0, 0};
        nr = n0 + row + 96;
        pw3 = (nr < V_) ? *(const float4*)&W[(size_t)nr * H_ + k0 + cg * 4] : float4{0, 0, 0, 0};
    };

    loadTile(kBeg);

    for (int k0 = kBeg; k0 < kEnd; k0 += 32) {
        __syncthreads();  // previous tile consumed
        {
            const float* f0 = (const float*)&pa0;
            const float* f1 = (const float*)&pa1;
            const float* g0 = (const float*)&pw0;
            const float* g1 = (const float*)&pw1;
            const float* g2 = (const float*)&pw2;
            const float* g3 = (const float*)&pw3;
#pragma unroll
            for (int j = 0; j < 4; j++) {
                int kk = cg * 4 + j;
                As[kk * 68 + swzi(kk, row)] = f0[j];
                As[kk * 68 + swzi(kk, row + 32)] = f1[j];
                Ws[kk * 132 + swzi(kk, row)] = g0[j];
                Ws[kk * 132 + swzi(kk, row + 32)] = g1[j];
                Ws[kk * 132 + swzi(kk, row + 64)] = g2[j];
                Ws[kk * 132 + swzi(kk, row + 96)] = g3[j];
            }
        }
        __syncthreads();
        if (k0 + 32 < kEnd) loadTile(k0 + 32);  // overlap with compute below

#pragma unroll
        for (int kk = 0; kk < 32; kk++) {
            int cgk = (kk >> 2) & 7;
            float4 av = *(const float4*)&As[kk * 68 + ((ty ^ cgk) << 2)];
            float4 w0 = *(const float4*)&Ws[kk * 132 + ((tx ^ cgk) << 2)];
            float4 w1 = *(const float4*)&Ws[kk * 132 + (((16 + tx) ^ cgk) << 2)];
            float a0 = av.x, a1 = av.y, a2 = av.z, a3 = av.w;
            acc[0][0] += a0 * w0.x; acc[0][1] += a0 * w0.y; acc[0][2] += a0 * w0.z; acc[0][3] += a0 * w0.w;
            acc[0][4] += a0 * w1.x; acc[0][5] += a0 * w1.y; acc[0][6] += a0 * w1.z; acc[0][7] += a0 * w1.w;
            acc[1][0] += a1 * w0.x; acc[1][1] += a1 * w0.y; acc[1][2] += a1 * w0.z; acc[1][3] += a1 * w0.w;
            acc[1][4] += a1 * w1.x; acc[1][5] += a1 * w1.y; acc[1][6] += a1 * w1.z; acc[1][7] += a1 * w1.w;
            acc[2][0] += a2 * w0.x; acc[2][1] += a2 * w0.y; acc[2][2] += a2 * w0.z; acc[2][3] += a2 * w0.w;
            acc[2][4] += a2 * w1.x; acc[2][5] += a2 * w1.y; acc[2][6] += a2 * w1.z; acc[2][7] += a2 * w1.w;
            acc[3][0] += a3 * w0.x; acc[3][1] += a3 * w0.y; acc[3][2] += a3 * w0.z; acc[3][3] += a3 * w0.w;
            acc[3][4] += a3 * w1.x; acc[3][5] += a3 * w1.y; acc[3][6] += a3 * w1.z; acc[3][7] += a3 * w1.w;
        }
    }

    float* Pp = P + (size_t)ks * 64 * VPAD;
#pragma unroll
    for (int i = 0; i < 4; i++) {
        int m = ty * 4 + i;
#pragma unroll
        for (int j = 0; j < 8; j++) {
            int n = n0 + (j < 4 ? tx * 4 + j : 64 + tx * 4 + (j - 4));
            Pp[(size_t)m * VPAD + n] = acc[i][j];
        }
    }
}

// ---------------------------------------------------------------------------
// Output combine: out[b][n] = P0[b][n] + P1[b][n] + bias[n]
__global__ __launch_bounds__(256) void out_combine_k(const float* __restrict__ P,
                                                     const float* __restrict__ bias,
                                                     float* __restrict__ out) {
    int n = blockIdx.x * 256 + threadIdx.x;
    int b = blockIdx.y;
    if (n < V_) {
        out[(size_t)b * V_ + n] = P[(size_t)b * VPAD + n] +
                                  P[(size_t)64 * VPAD + (size_t)b * VPAD + n] + bias[n];
    }
}

// ---------------------------------------------------------------------------
extern "C" void kernel_launch(void* const* d_in, const int* in_sizes, int n_in,
                              void* d_out, int out_size, void* d_ws, size_t ws_size,
                              hipStream_t stream) {
    const int* seq = (const int*)d_in[0];
    const float* last_hidden = (const float*)d_in[1];
    const float* enc = (const float*)d_in[2];
    const float* emb = (const float*)d_in[3];
    const float* w_ih = (const float*)d_in[4];
    const float* w_hh = (const float*)d_in[5];
    const float* b_ih = (const float*)d_in[6];
    const float* b_hh = (const float*)d_in[7];
    const float* concat_w = (const float*)d_in[8];
    const float* concat_b = (const float*)d_in[9];
    const float* out_w = (const float*)d_in[10];
    const float* out_b = (const float*)d_in[11];

    float* out = (float*)d_out;                           // (B,V)
    float* out_hidden = out + (size_t)B_ * V_;            // (L,B,H)
    float* out_attn = out_hidden + (size_t)L_ * B_ * H_;  // (B,1,S)

    float* ws = (float*)d_ws;
    float* x0 = ws;                        // 65536
    float* gatesP = x0 + 65536;            // 4*64*6144 = 1572864
    float* scores = gatesP + 1572864;      // 65536
    float* chunkMax = scores + 65536;      // 1024
    float* ctxPart = chunkMax + 1024;      // 1048576
    float* concat_in = ctxPart + 1048576;  // 131072
    float* concatP = concat_in + 131072;   // 524288
    float* concat_out = concatP + 524288;  // 65536
    float* outP = concat_out + 65536;      // 2*64*50304 = 6438912

    // 1. Embedding
    embed_k<<<256, 256, 0, stream>>>(seq, emb, x0);

    // 2. GRU layers
    for (int l = 0; l < L_; l++) {
        const float* xl = (l == 0) ? x0 : out_hidden + (size_t)(l - 1) * B_ * H_;
        const float* hl = last_hidden + (size_t)l * B_ * H_;
        gemm_m64<<<dim3(N_GATES / 64, 4), 256, 0, stream>>>(
            xl, hl, H_,
            w_ih + (size_t)l * G3H * H_, w_hh + (size_t)l * G3H * H_, H_, G3H,
            gatesP, N_GATES, H_);
        gru_combine_k<<<256, 256, 0, stream>>>(gatesP, b_ih + (size_t)l * G3H,
                                               b_hh + (size_t)l * G3H, hl,
                                               out_hidden + (size_t)l * B_ * H_);
    }
    const float* rnn = out_hidden + (size_t)2 * B_ * H_;

    // 3. Fused attention (single enc pass) + combine/assemble
    attn_pass1<<<1024, 256, 0, stream>>>(rnn, enc, scores, ctxPart, chunkMax);
    attn_pass2<<<64, 256, 0, stream>>>(scores, chunkMax, ctxPart, rnn,
                                       out_attn, concat_in);

    // 4. Concat GEMM (K=2048, 8-way K-split) + tanh combine
    gemm_m64<<<dim3(16, 8), 256, 0, stream>>>(
        concat_in, concat_in, 2048, concat_w, concat_w, 2048, 1 << 30,
        concatP, H_, 2048);
    concat_combine_k<<<256, 256, 0, stream>>>(concatP, concat_b, concat_out);

    // 5. Output GEMM (K-split 2) + combine
    gemm_out_k<<<dim3(VPAD / 128, 2), 256, 0, stream>>>(concat_out, out_w, outP);
    out_combine_k<<<dim3((V_ + 255) / 256, 64), 256, 0, stream>>>(outP, out_b, out);
}

// Round 4
// 258.451 us; speedup vs baseline: 1.2934x; 1.1090x over previous
//
#include <hip/hip_runtime.h>
#include <hip/hip_bf16.h>
#include <float.h>

#define B_ 64
#define H_ 1024
#define S_ 1024
#define V_ 50257
#define L_ 3
#define G3H 3072      // 3*H
#define N_GATES 6144  // 2*3H fused gi|gh

typedef __attribute__((ext_vector_type(8))) short short8v;  // 8 bf16 (4 VGPRs)
typedef __attribute__((ext_vector_type(4))) float f32x4;    // MFMA accumulator

// round-to-nearest f32 -> bf16 bits
__device__ __forceinline__ ushort rnd_bf16(float x) {
    uint u = __float_as_uint(x);
    return (ushort)((u + 0x7fffu + ((u >> 16) & 1u)) >> 16);
}

// exact split x = hi + lo (hi = truncated bf16, lo = rounded residual)
__device__ __forceinline__ void split_bf16(float x, ushort& hi, ushort& lo) {
    uint u = __float_as_uint(x);
    uint h = u & 0xffff0000u;
    hi = (ushort)(h >> 16);
    float r = x - __uint_as_float(h);
    uint ur = __float_as_uint(r);
    lo = (ushort)((ur + 0x7fffu + ((ur >> 16) & 1u)) >> 16);
}

// LDS XOR swizzle for fp32 GEMMs: permute 16B chunks within a row.
__device__ __forceinline__ int swzi(int kk, int m) {
    return (((m >> 2) ^ ((kk >> 2) & 7)) << 2) | (m & 3);
}

// ---------------------------------------------------------------------------
// Embedding gather: x0[b][h] = emb[seq[b]][h]
__global__ __launch_bounds__(256) void embed_k(const int* __restrict__ seq,
                                               const float* __restrict__ emb,
                                               float* __restrict__ x0) {
    int idx = blockIdx.x * 256 + threadIdx.x;  // 65536 total
    int b = idx >> 10, h = idx & 1023;
    x0[idx] = emb[(size_t)seq[b] * H_ + h];
}

// ---------------------------------------------------------------------------
// Generic M=64 fp32 GEMM (GRU gates + concat): C[m][n] = sum_k A[m][k]*W[n][k]
// Tile 64x64, KT=32, swizzled LDS, K-split partials to Cpart[kc][m][n].
__global__ __launch_bounds__(256) void gemm_m64(
    const float* __restrict__ A0, const float* __restrict__ A1, int lda,
    const float* __restrict__ W0, const float* __restrict__ W1, int ldw,
    int Nhalf, float* __restrict__ Cpart, int N, int K) {
    __shared__ float As[32 * 68];
    __shared__ float Ws[32 * 68];

    int n0 = blockIdx.x * 64;
    const float* A = A0;
    const float* W = W0;
    int ncol0 = n0;
    if (n0 >= Nhalf) { A = A1; W = W1; ncol0 = n0 - Nhalf; }

    int tid = threadIdx.x;
    int tx = tid & 15, ty = tid >> 4;
    int row = tid >> 3;  // 0..31
    int cg = tid & 7;    // k group of 4

    float acc[4][4] = {};

    int kChunk = K / gridDim.y;
    int k0b = blockIdx.y * kChunk;

    for (int k0 = k0b; k0 < k0b + kChunk; k0 += 32) {
        float4 a0 = *(const float4*)&A[(size_t)row * lda + k0 + cg * 4];
        float4 a1 = *(const float4*)&A[(size_t)(row + 32) * lda + k0 + cg * 4];
        float4 w0 = *(const float4*)&W[(size_t)(ncol0 + row) * ldw + k0 + cg * 4];
        float4 w1 = *(const float4*)&W[(size_t)(ncol0 + row + 32) * ldw + k0 + cg * 4];
        const float* fa0 = (const float*)&a0;
        const float* fa1 = (const float*)&a1;
        const float* fw0 = (const float*)&w0;
        const float* fw1 = (const float*)&w1;
#pragma unroll
        for (int j = 0; j < 4; j++) {
            int kk = cg * 4 + j;
            As[kk * 68 + swzi(kk, row)] = fa0[j];
            As[kk * 68 + swzi(kk, row + 32)] = fa1[j];
            Ws[kk * 68 + swzi(kk, row)] = fw0[j];
            Ws[kk * 68 + swzi(kk, row + 32)] = fw1[j];
        }
        __syncthreads();
#pragma unroll
        for (int kk = 0; kk < 32; kk++) {
            int cgk = (kk >> 2) & 7;
            float4 av = *(const float4*)&As[kk * 68 + ((ty ^ cgk) << 2)];
            float4 wv = *(const float4*)&Ws[kk * 68 + ((tx ^ cgk) << 2)];
            acc[0][0] += av.x * wv.x; acc[0][1] += av.x * wv.y;
            acc[0][2] += av.x * wv.z; acc[0][3] += av.x * wv.w;
            acc[1][0] += av.y * wv.x; acc[1][1] += av.y * wv.y;
            acc[1][2] += av.y * wv.z; acc[1][3] += av.y * wv.w;
            acc[2][0] += av.z * wv.x; acc[2][1] += av.z * wv.y;
            acc[2][2] += av.z * wv.z; acc[2][3] += av.z * wv.w;
            acc[3][0] += av.w * wv.x; acc[3][1] += av.w * wv.y;
            acc[3][2] += av.w * wv.z; acc[3][3] += av.w * wv.w;
        }
        __syncthreads();
    }

    float* P = Cpart + (size_t)blockIdx.y * 64 * N;
#pragma unroll
    for (int i = 0; i < 4; i++) {
        int m = ty * 4 + i;
#pragma unroll
        for (int j = 0; j < 4; j++) {
            int n = n0 + tx * 4 + j;
            P[(size_t)m * N + n] = acc[i][j];
        }
    }
}

// ---------------------------------------------------------------------------
// GRU gate combine: 4 K-split partials of fused [gi | gh] + biases -> h_out
__global__ __launch_bounds__(256) void gru_combine_k(
    const float* __restrict__ P, const float* __restrict__ b_ih,
    const float* __restrict__ b_hh, const float* __restrict__ hprev,
    float* __restrict__ hout) {
    int idx = blockIdx.x * 256 + threadIdx.x;  // 65536
    int b = idx >> 10, j = idx & 1023;
    const size_t stride = (size_t)64 * N_GATES;
    const float* rowp = P + (size_t)b * N_GATES;

    float ir = 0.f, iz = 0.f, in_ = 0.f, hr = 0.f, hz = 0.f, hn = 0.f;
#pragma unroll
    for (int kc = 0; kc < 4; kc++) {
        const float* p = rowp + kc * stride;
        ir += p[j];        iz += p[j + 1024];        in_ += p[j + 2048];
        hr += p[3072 + j]; hz += p[3072 + j + 1024]; hn += p[3072 + j + 2048];
    }
    ir += b_ih[j]; iz += b_ih[j + 1024]; in_ += b_ih[j + 2048];
    hr += b_hh[j]; hz += b_hh[j + 1024]; hn += b_hh[j + 2048];

    float r = 1.f / (1.f + __expf(-(ir + hr)));
    float z = 1.f / (1.f + __expf(-(iz + hz)));
    float n = tanhf(in_ + r * hn);
    float hp = hprev[idx];
    hout[idx] = (1.f - z) * n + z * hp;
}

// ---------------------------------------------------------------------------
// Fused attention pass 1: one enc read -> raw scores + online-softmax context
// partials. grid = 64 b * 16 sc; 4 waves/block, each wave owns 16 s rows.
__global__ __launch_bounds__(256) void attn_pass1(
    const float* __restrict__ rnn, const float* __restrict__ enc,
    float* __restrict__ scores, float* __restrict__ ctxPart,
    float* __restrict__ chunkMax) {
    __shared__ float lm[4];
    __shared__ float lc[4][1024];

    int bid = blockIdx.x;
    int b = bid >> 4, scv = bid & 15;
    int tid = threadIdx.x;
    int w = tid >> 6, lane = tid & 63;

    const float4* rr = (const float4*)(rnn + (size_t)b * H_);
    float4 r0 = rr[0 * 64 + lane], r1 = rr[1 * 64 + lane];
    float4 r2 = rr[2 * 64 + lane], r3 = rr[3 * 64 + lane];

    float m = -FLT_MAX;
    float4 c0 = {0, 0, 0, 0}, c1 = {0, 0, 0, 0}, c2 = {0, 0, 0, 0}, c3 = {0, 0, 0, 0};

    int s0 = scv * 64 + w * 16;
    for (int si = 0; si < 16; si++) {
        int s = s0 + si;
        const float4* er = (const float4*)(enc + ((size_t)s * B_ + b) * H_);
        float4 e0 = er[0 * 64 + lane], e1 = er[1 * 64 + lane];
        float4 e2 = er[2 * 64 + lane], e3 = er[3 * 64 + lane];

        float d = e0.x * r0.x + e0.y * r0.y + e0.z * r0.z + e0.w * r0.w;
        d += e1.x * r1.x + e1.y * r1.y + e1.z * r1.z + e1.w * r1.w;
        d += e2.x * r2.x + e2.y * r2.y + e2.z * r2.z + e2.w * r2.w;
        d += e3.x * r3.x + e3.y * r3.y + e3.z * r3.z + e3.w * r3.w;
#pragma unroll
        for (int off = 32; off; off >>= 1) d += __shfl_xor(d, off, 64);
        if (lane == 0) scores[(size_t)b * S_ + s] = d;

        if (d > m) {  // wave-uniform (d identical on all lanes)
            float scale = __expf(m - d);
            c0.x *= scale; c0.y *= scale; c0.z *= scale; c0.w *= scale;
            c1.x *= scale; c1.y *= scale; c1.z *= scale; c1.w *= scale;
            c2.x *= scale; c2.y *= scale; c2.z *= scale; c2.w *= scale;
            c3.x *= scale; c3.y *= scale; c3.z *= scale; c3.w *= scale;
            m = d;
        }
        float p = __expf(d - m);
        c0.x += p * e0.x; c0.y += p * e0.y; c0.z += p * e0.z; c0.w += p * e0.w;
        c1.x += p * e1.x; c1.y += p * e1.y; c1.z += p * e1.z; c1.w += p * e1.w;
        c2.x += p * e2.x; c2.y += p * e2.y; c2.z += p * e2.z; c2.w += p * e2.w;
        c3.x += p * e3.x; c3.y += p * e3.y; c3.z += p * e3.z; c3.w += p * e3.w;
    }

    if (lane == 0) lm[w] = m;
    __syncthreads();
    float M = fmaxf(fmaxf(lm[0], lm[1]), fmaxf(lm[2], lm[3]));
    float sw = __expf(m - M);
    float4* lw = (float4*)&lc[w][0];
    float4 t;
    t.x = c0.x * sw; t.y = c0.y * sw; t.z = c0.z * sw; t.w = c0.w * sw; lw[0 * 64 + lane] = t;
    t.x = c1.x * sw; t.y = c1.y * sw; t.z = c1.z * sw; t.w = c1.w * sw; lw[1 * 64 + lane] = t;
    t.x = c2.x * sw; t.y = c2.y * sw; t.z = c2.z * sw; t.w = c2.w * sw; lw[2 * 64 + lane] = t;
    t.x = c3.x * sw; t.y = c3.y * sw; t.z = c3.z * sw; t.w = c3.w * sw; lw[3 * 64 + lane] = t;
    __syncthreads();

    float4 s4 = *(const float4*)&lc[0][tid * 4];
    float4 a1 = *(const float4*)&lc[1][tid * 4];
    float4 a2 = *(const float4*)&lc[2][tid * 4];
    float4 a3 = *(const float4*)&lc[3][tid * 4];
    s4.x += a1.x + a2.x + a3.x; s4.y += a1.y + a2.y + a3.y;
    s4.z += a1.z + a2.z + a3.z; s4.w += a1.w + a2.w + a3.w;
    *(float4*)&ctxPart[(size_t)bid * H_ + tid * 4] = s4;
    if (tid == 0) chunkMax[bid] = M;
}

// ---------------------------------------------------------------------------
// Attention pass 2 (per b): global softmax -> attn output, rescale+sum chunk
// contexts, assemble concat_in = [rnn | ctx].
__global__ __launch_bounds__(256) void attn_pass2(
    const float* __restrict__ scores, const float* __restrict__ chunkMax,
    const float* __restrict__ ctxPart, const float* __restrict__ rnn,
    float* __restrict__ attn, float* __restrict__ concat_in) {
    __shared__ float red[256];
    int b = blockIdx.x, tid = threadIdx.x;

    float v[4];
#pragma unroll
    for (int q = 0; q < 4; q++) v[q] = scores[(size_t)b * S_ + q * 256 + tid];
    float mx = fmaxf(fmaxf(v[0], v[1]), fmaxf(v[2], v[3]));
    red[tid] = mx; __syncthreads();
    for (int s = 128; s; s >>= 1) {
        if (tid < s) red[tid] = fmaxf(red[tid], red[tid + s]);
        __syncthreads();
    }
    float M = red[0]; __syncthreads();
    float e[4], sum = 0.f;
#pragma unroll
    for (int q = 0; q < 4; q++) { e[q] = __expf(v[q] - M); sum += e[q]; }
    red[tid] = sum; __syncthreads();
    for (int s = 128; s; s >>= 1) {
        if (tid < s) red[tid] += red[tid + s];
        __syncthreads();
    }
    float inv = 1.f / red[0];
#pragma unroll
    for (int q = 0; q < 4; q++) attn[(size_t)b * S_ + q * 256 + tid] = e[q] * inv;

    float4 acc = {0, 0, 0, 0};
#pragma unroll
    for (int c = 0; c < 16; c++) {
        float scl = __expf(chunkMax[b * 16 + c] - M);
        float4 part = *(const float4*)&ctxPart[((size_t)b * 16 + c) * H_ + tid * 4];
        acc.x += scl * part.x; acc.y += scl * part.y;
        acc.z += scl * part.z; acc.w += scl * part.w;
    }
    acc.x *= inv; acc.y *= inv; acc.z *= inv; acc.w *= inv;
    *(float4*)&concat_in[(size_t)b * 2048 + 1024 + tid * 4] = acc;
    *(float4*)&concat_in[(size_t)b * 2048 + tid * 4] =
        *(const float4*)&rnn[(size_t)b * H_ + tid * 4];
}

// ---------------------------------------------------------------------------
// Concat combine: sum 8 K-split partials + bias, tanh; emit exact bf16
// hi/lo split of the result for the MFMA output GEMM.
__global__ __launch_bounds__(256) void concat_combine_k(const float* __restrict__ P,
                                                        const float* __restrict__ bias,
                                                        ushort* __restrict__ Ahi,
                                                        ushort* __restrict__ Alo) {
    int idx = blockIdx.x * 256 + threadIdx.x;  // 65536
    int b = idx >> 10, h = idx & 1023;
    float s = 0.f;
#pragma unroll
    for (int kc = 0; kc < 8; kc++) s += P[(size_t)kc * 65536 + (size_t)b * H_ + h];
    float v = tanhf(s + bias[h]);
    ushort hi, lo;
    split_bf16(v, hi, lo);
    Ahi[idx] = hi;
    Alo[idx] = lo;
}

// ---------------------------------------------------------------------------
// Output GEMM via bf16 MFMA, LDS-free streaming.
// out[64][V] = (Ahi+Alo)[64][1024] x bf16(W)[V][1024]^T + bias.
// Grid: 786 blocks x 128 threads; each wave owns 32 cols (2 n-tiles), M=64.
// mfma_f32_16x16x32_bf16 fragments: A lane l: row=l&15, k=(l>>4)*8+j;
// B lane l: col=l&15, k=(l>>4)*8+j (W rows are contiguous in k -> direct
// 32B global reads, full 128B lines consumed per 4-lane-group).
__global__ __launch_bounds__(128) void gemm_out_bf16(
    const ushort* __restrict__ Ahi, const ushort* __restrict__ Alo,
    const float* __restrict__ W, const float* __restrict__ bias,
    float* __restrict__ out) {
    int tid = threadIdx.x;
    int w = tid >> 6, l = tid & 63;
    int lr = l & 15;   // row (A) / col (B) within 16-tile
    int lk = l >> 4;   // k-subgroup (0..3)

    int n0 = blockIdx.x * 64 + w * 32;
    int na = n0 + lr;        // n-tile 0 column for this lane
    int nb = n0 + 16 + lr;   // n-tile 1 column
    bool va = na < V_, vb = nb < V_;
    const float* Wa = W + (size_t)na * H_;
    const float* Wb = W + (size_t)nb * H_;

    f32x4 acc[4][2];
#pragma unroll
    for (int mt = 0; mt < 4; mt++)
#pragma unroll
        for (int nt = 0; nt < 2; nt++) acc[mt][nt] = (f32x4){0.f, 0.f, 0.f, 0.f};

    union SV { short8v v; ushort u[8]; };

    for (int k0 = 0; k0 < H_; k0 += 32) {
        int kb = k0 + lk * 8;

        // A fragments (hi/lo), 16B loads, L2-resident
        short8v ah[4], al[4];
#pragma unroll
        for (int mt = 0; mt < 4; mt++) {
            int mr = mt * 16 + lr;
            ah[mt] = *(const short8v*)&Ahi[(size_t)mr * H_ + kb];
            al[mt] = *(const short8v*)&Alo[(size_t)mr * H_ + kb];
        }

        // W fragments: 8 contiguous fp32 per lane per tile -> rounded bf16
        SV wfa, wfb;
        {
            float4 x0 = va ? *(const float4*)&Wa[kb] : float4{0, 0, 0, 0};
            float4 x1 = va ? *(const float4*)&Wa[kb + 4] : float4{0, 0, 0, 0};
            float4 y0 = vb ? *(const float4*)&Wb[kb] : float4{0, 0, 0, 0};
            float4 y1 = vb ? *(const float4*)&Wb[kb + 4] : float4{0, 0, 0, 0};
            const float* fx0 = (const float*)&x0;
            const float* fx1 = (const float*)&x1;
            const float* fy0 = (const float*)&y0;
            const float* fy1 = (const float*)&y1;
#pragma unroll
            for (int j = 0; j < 4; j++) {
                wfa.u[j] = rnd_bf16(fx0[j]);
                wfa.u[j + 4] = rnd_bf16(fx1[j]);
                wfb.u[j] = rnd_bf16(fy0[j]);
                wfb.u[j + 4] = rnd_bf16(fy1[j]);
            }
        }

#pragma unroll
        for (int mt = 0; mt < 4; mt++) {
            acc[mt][0] = __builtin_amdgcn_mfma_f32_16x16x32_bf16(ah[mt], wfa.v, acc[mt][0], 0, 0, 0);
            acc[mt][0] = __builtin_amdgcn_mfma_f32_16x16x32_bf16(al[mt], wfa.v, acc[mt][0], 0, 0, 0);
            acc[mt][1] = __builtin_amdgcn_mfma_f32_16x16x32_bf16(ah[mt], wfb.v, acc[mt][1], 0, 0, 0);
            acc[mt][1] = __builtin_amdgcn_mfma_f32_16x16x32_bf16(al[mt], wfb.v, acc[mt][1], 0, 0, 0);
        }
    }

    // Epilogue: D lane l reg r -> row=(l>>4)*4+r (+ mt*16), col=l&15 tile col.
    float biasA = va ? bias[na] : 0.f;
    float biasB = vb ? bias[nb] : 0.f;
#pragma unroll
    for (int mt = 0; mt < 4; mt++) {
#pragma unroll
        for (int r = 0; r < 4; r++) {
            int row = mt * 16 + lk * 4 + r;
            if (va) out[(size_t)row * V_ + na] = acc[mt][0][r] + biasA;
            if (vb) out[(size_t)row * V_ + nb] = acc[mt][1][r] + biasB;
        }
    }
}

// ---------------------------------------------------------------------------
extern "C" void kernel_launch(void* const* d_in, const int* in_sizes, int n_in,
                              void* d_out, int out_size, void* d_ws, size_t ws_size,
                              hipStream_t stream) {
    const int* seq = (const int*)d_in[0];
    const float* last_hidden = (const float*)d_in[1];
    const float* enc = (const float*)d_in[2];
    const float* emb = (const float*)d_in[3];
    const float* w_ih = (const float*)d_in[4];
    const float* w_hh = (const float*)d_in[5];
    const float* b_ih = (const float*)d_in[6];
    const float* b_hh = (const float*)d_in[7];
    const float* concat_w = (const float*)d_in[8];
    const float* concat_b = (const float*)d_in[9];
    const float* out_w = (const float*)d_in[10];
    const float* out_b = (const float*)d_in[11];

    float* out = (float*)d_out;                           // (B,V)
    float* out_hidden = out + (size_t)B_ * V_;            // (L,B,H)
    float* out_attn = out_hidden + (size_t)L_ * B_ * H_;  // (B,1,S)

    float* ws = (float*)d_ws;
    float* x0 = ws;                        // 65536
    float* gatesP = x0 + 65536;            // 4*64*6144 = 1572864
    float* scores = gatesP + 1572864;      // 65536
    float* chunkMax = scores + 65536;      // 1024
    float* ctxPart = chunkMax + 1024;      // 1048576
    float* concat_in = ctxPart + 1048576;  // 131072
    float* concatP = concat_in + 131072;   // 524288
    ushort* Ahi = (ushort*)(concatP + 524288);  // 65536 ushort = 32768 floats
    ushort* Alo = Ahi + 65536;                  // 65536 ushort

    // 1. Embedding
    embed_k<<<256, 256, 0, stream>>>(seq, emb, x0);

    // 2. GRU layers
    for (int l = 0; l < L_; l++) {
        const float* xl = (l == 0) ? x0 : out_hidden + (size_t)(l - 1) * B_ * H_;
        const float* hl = last_hidden + (size_t)l * B_ * H_;
        gemm_m64<<<dim3(N_GATES / 64, 4), 256, 0, stream>>>(
            xl, hl, H_,
            w_ih + (size_t)l * G3H * H_, w_hh + (size_t)l * G3H * H_, H_, G3H,
            gatesP, N_GATES, H_);
        gru_combine_k<<<256, 256, 0, stream>>>(gatesP, b_ih + (size_t)l * G3H,
                                               b_hh + (size_t)l * G3H, hl,
                                               out_hidden + (size_t)l * B_ * H_);
    }
    const float* rnn = out_hidden + (size_t)2 * B_ * H_;

    // 3. Fused attention (single enc pass) + combine/assemble
    attn_pass1<<<1024, 256, 0, stream>>>(rnn, enc, scores, ctxPart, chunkMax);
    attn_pass2<<<64, 256, 0, stream>>>(scores, chunkMax, ctxPart, rnn,
                                       out_attn, concat_in);

    // 4. Concat GEMM (K=2048, 8-way K-split) + tanh combine (+ bf16 split)
    gemm_m64<<<dim3(16, 8), 256, 0, stream>>>(
        concat_in, concat_in, 2048, concat_w, concat_w, 2048, 1 << 30,
        concatP, H_, 2048);
    concat_combine_k<<<256, 256, 0, stream>>>(concatP, concat_b, Ahi, Alo);

    // 5. Output GEMM: bf16 MFMA, LDS-free, direct store with bias
    gemm_out_bf16<<<786, 128, 0, stream>>>(Ahi, Alo, out_w, out_b, out);
}